// Round 3
// baseline (2450.464 us; speedup 1.0000x reference)
//
#include <hip/hip_runtime.h>
#include <hip/hip_bf16.h>

#define B_  256
#define T_  256
#define F_  64
#define U_  512
#define NG_ 2048   // 4*U
#define BU_ (B_ * U_)

typedef __attribute__((ext_vector_type(8))) short short8;
typedef __attribute__((ext_vector_type(16))) float floatx16;

__device__ __forceinline__ unsigned short f2bf(float f) {
    union { float f; unsigned int u; } v; v.f = f;
    unsigned int u = v.u;
    return (unsigned short)((u + 0x7FFFu + ((u >> 16) & 1u)) >> 16);
}
__device__ __forceinline__ float bf2f(unsigned short s) {
    union { unsigned int u; float f; } v; v.u = ((unsigned int)s) << 16;
    return v.f;
}

__global__ void cast_x_kernel(const float* __restrict__ x,
                              unsigned short* __restrict__ xb, int n) {
    int i = blockIdx.x * blockDim.x + threadIdx.x;
    if (i < n) xb[i] = f2bf(x[i]);
}

// Pack weights into 32x32x16 MFMA B-fragments, per unit-group (16 units -> 64
// block-local gate cols = 2 n32 tiles: [i16|f16] [g16|o16]).
__global__ void pack32_kernel(const float* __restrict__ W, const float* __restrict__ Uw,
                              unsigned short* __restrict__ dst, int KT, int KX) {
    long tid = (long)blockIdx.x * blockDim.x + threadIdx.x;
    long total = 32L * 2 * KT * 512;
    if (tid >= total) return;
    int j    = (int)(tid & 7);
    int lane = (int)((tid >> 3) & 63);
    int p512 = (int)(tid >> 9);
    int kt   = p512 % KT;
    int q    = p512 / KT;
    int nt   = q & 1;
    int ug   = q >> 1;
    int c    = nt * 32 + (lane & 31);
    int srcn = (c >> 4) * U_ + ug * 16 + (c & 15);
    int k    = kt * 16 + (lane >> 5) * 8 + j;
    float v  = (k < KX) ? W[(long)k * NG_ + srcn] : Uw[(long)(k - KX) * NG_ + srcn];
    dst[tid] = f2bf(v);
}

// LLC-coherent 16-B load, NON-atomic: batched issue, latency overlaps.
__device__ __forceinline__ short8 llc_load(const unsigned short* p) {
    short8 r;
    asm volatile("global_load_dwordx4 %0, %1, off sc0 sc1" : "=v"(r) : "v"(p));
    return r;
}
// 8-B coherent store (4 bf16 units).
__device__ __forceinline__ void llc_store8(unsigned short* p, unsigned long long v) {
    asm volatile("global_store_dwordx2 %0, %1, off sc0 sc1" :: "v"(p), "v"(v) : "memory");
}
#define VMWAIT(N) asm volatile("s_waitcnt vmcnt(" #N ")" ::: "memory")
__device__ __forceinline__ void dep8(short8& x) { asm volatile("" : "+v"(x)); }

#define MFMA32(a, b, c) __builtin_amdgcn_mfma_f32_32x32x16_bf16(a, b, c, 0, 0, 0)

// Single-line monotonic counter wait (64 lanes same addr -> one LLC req/round).
__device__ __forceinline__ void wait_ge(const int* p, int tgt) {
    int guard = 0;
    for (;;) {
        int v = __hip_atomic_load(p, __ATOMIC_RELAXED, __HIP_MEMORY_SCOPE_AGENT);
        if (v >= tgt) break;
        __builtin_amdgcn_s_sleep(1);
        if (++guard > (1 << 19)) break;   // fail visibly, never hang
    }
}

// 2-wave LDS generation barrier. lane0 publishes seq; all lanes spin on the
// partner's slot (same-addr broadcast read, conflict-free). lgkmcnt(0) before
// the publish orders prior LDS writes; sched_barrier stops hoisting of the
// consumer's LDS reads above the spin (rule #18).
__device__ __forceinline__ void tbar(volatile int* mine, volatile int* other,
                                     int seq, int lane) {
    asm volatile("s_waitcnt lgkmcnt(0)" ::: "memory");
    if (lane == 0) *mine = seq;
    for (;;) { if (*other >= seq) break; }
    __builtin_amdgcn_sched_barrier(0);
}

// Persistent 2-layer LSTM, wave-specialized: waves 0-1 = layer-1 team,
// waves 2-3 = layer-2 team. Teams share NO barrier -> the two per-step
// latency chains (poll + coherent loads + reduce + store-drain + signal)
// overlap; iteration period ~= max(chainA, chainB) instead of the sum.
// Counters: c1 (+1 per block per L1 step), c2 (+1 per L2 step).
//  team1(k): wait c1>=32k (peers' L1 k-1), c2>=32(k-3) (h1 ring WAR).
//  team2(k): w2 waits c1>=32k (h1[k-1]); w3 waits c2>=32(k-1) (h2[k-2]).
__global__ __launch_bounds__(256, 1) void lstm_persist(
    const unsigned short* __restrict__ xb,
    const unsigned short* __restrict__ P1,
    const unsigned short* __restrict__ P2,
    const float* __restrict__ b1, const float* __restrict__ b2,
    unsigned short* __restrict__ h1r, unsigned short* __restrict__ h2r,
    int* flags1, int* flags2)
{
    const int bid  = blockIdx.x;     // 0..255
    const int mo   = bid & 7;        // m-octile == XCD (locality heuristic)
    const int ug   = bid >> 3;       // 32 unit-groups of 16 units
    const int tid  = threadIdx.x;
    const int w    = tid >> 6;       // wave 0..3
    const int lane = tid & 63;
    const int arow = lane & 31;
    const int koff = (lane >> 5) * 8;
    const int row  = mo * 32 + arow;

    int* c1 = flags1 + mo * 32;   // one 128-B line per mo, layer 1
    int* c2 = flags2 + mo * 32;   // one 128-B line per mo, layer 2

    __shared__ float redA[2][2][32][33];   // team1 partials
    __shared__ float redB[2][2][32][33];   // team2 partials
    __shared__ float cst1[32][16];
    __shared__ float cst2[32][16];
    __shared__ float bias1_s[64], bias2_s[64];
    __shared__ int   ts1[2], ts2[2];       // team barrier slots

    for (int i = tid; i < 512; i += 256) {
        cst1[i >> 4][i & 15] = 0.f;
        cst2[i >> 4][i & 15] = 0.f;
    }
    if (tid < 64) {
        bias1_s[tid] = b1[(tid >> 4) * U_ + ug * 16 + (tid & 15)];
        bias2_s[tid] = b2[(tid >> 4) * U_ + ug * 16 + (tid & 15)];
    }
    if (tid < 2) { ts1[tid] = 0; ts2[tid] = 0; }

    if (w < 2) {
        // ================= TEAM 1 : layer-1, waves 0/1 =================
        const int l = w;
        // B-frags: 18 ktiles each (w0: 0..17 = x0..3 + h0..13; w1: 18..35 = h14..31)
        short8 bf0[18], bf1[18];
        {
            const unsigned short* base = P1 + (size_t)ug * (2 * 36 * 512);
            #pragma unroll
            for (int i = 0; i < 18; ++i) {
                bf0[i] = *(const short8*)(base + ((size_t)(0 * 36 + w * 18 + i) * 64 + lane) * 8);
                bf1[i] = *(const short8*)(base + ((size_t)(1 * 36 + w * 18 + i) * 64 + lane) * 8);
            }
        }
        __syncthreads();   // one-time: LDS init + all prologues done

        volatile int* mine  = &ts1[l];
        volatile int* other = &ts1[1 - l];
        int seq = 0;

        for (int k = 0; k < T_; ++k) {
            if (k >= 1) wait_ge(c1, 32 * k);
            if (k >= 4) wait_ge(c2, 32 * (k - 3));
            __atomic_signal_fence(__ATOMIC_ACQUIRE);

            short8 ax[4]; short8 ah[18];
            const int nh = (k >= 1) ? ((l == 0) ? 14 : 18) : 0;
            if (l == 0) {
                const unsigned short* xbase = xb + ((size_t)row * T_ + k) * F_;
                #pragma unroll
                for (int i = 0; i < 4; ++i) ax[i] = *(const short8*)(xbase + i * 16 + koff);
            }
            if (nh) {
                const unsigned short* hb = h1r + (size_t)((k - 1) & 3) * BU_
                                           + (size_t)row * U_ + ((l == 0) ? 0 : 14 * 16);
                if (l == 0) {
                    #pragma unroll
                    for (int i = 0; i < 14; ++i) ah[i] = llc_load(hb + i * 16 + koff);
                } else {
                    #pragma unroll
                    for (int i = 0; i < 18; ++i) ah[i] = llc_load(hb + i * 16 + koff);
                }
            }

            floatx16 a0, a1;
            #pragma unroll
            for (int i = 0; i < 16; ++i) { a0[i] = 0.f; a1[i] = 0.f; }

            VMWAIT(0);
            if (l == 0) {
                #pragma unroll
                for (int j = 0; j < 4; ++j) {
                    dep8(ax[j]);
                    a0 = MFMA32(ax[j], bf0[j], a0);
                    a1 = MFMA32(ax[j], bf1[j], a1);
                }
                if (nh) {
                    #pragma unroll
                    for (int j = 0; j < 14; ++j) {
                        dep8(ah[j]);
                        a0 = MFMA32(ah[j], bf0[4 + j], a0);
                        a1 = MFMA32(ah[j], bf1[4 + j], a1);
                    }
                }
            } else if (nh) {
                #pragma unroll
                for (int j = 0; j < 18; ++j) {
                    dep8(ah[j]);
                    a0 = MFMA32(ah[j], bf0[j], a0);
                    a1 = MFMA32(ah[j], bf1[j], a1);
                }
            }

            #pragma unroll
            for (int r = 0; r < 16; ++r) {
                int rr = (r & 3) + 8 * (r >> 2) + 4 * (lane >> 5);
                redA[l][0][rr][arow] = a0[r];
                redA[l][1][rr][arow] = a1[r];
            }
            tbar(mine, other, ++seq, lane);

            {   // epilogue: 128 thr = 32 rows x 4 unit-quads
                int tt = l * 64 + lane;
                int r  = tt >> 2;
                int q  = tt & 3;
                unsigned int pk0 = 0, pk1 = 0;
                #pragma unroll
                for (int j = 0; j < 4; ++j) {
                    int u = q * 4 + j;
                    float zi = redA[0][0][r][u]      + redA[1][0][r][u];
                    float zf = redA[0][0][r][16 + u] + redA[1][0][r][16 + u];
                    float zg = redA[0][1][r][u]      + redA[1][1][r][u];
                    float zo = redA[0][1][r][16 + u] + redA[1][1][r][16 + u];
                    zi += bias1_s[u];      zf += bias1_s[16 + u];
                    zg += bias1_s[32 + u]; zo += bias1_s[48 + u];
                    float si = 1.f / (1.f + __expf(-zi));
                    float sf = 1.f / (1.f + __expf(-zf));
                    float so = 1.f / (1.f + __expf(-zo));
                    float gg = zg > 0.f ? zg : 0.f;
                    float cn = sf * cst1[r][u] + si * gg;
                    cst1[r][u] = cn;
                    float hn = so * (cn > 0.f ? cn : 0.f);
                    if (j < 2) pk0 |= ((unsigned int)f2bf(hn)) << (16 * j);
                    else       pk1 |= ((unsigned int)f2bf(hn)) << (16 * (j - 2));
                }
                unsigned long long pk = ((unsigned long long)pk1 << 32) | pk0;
                unsigned short* hp = h1r + (size_t)(k & 3) * BU_
                                     + (size_t)(mo * 32 + r) * U_ + ug * 16 + q * 4;
                llc_store8(hp, pk);
            }
            VMWAIT(0);                       // own h1 stores drained
            tbar(mine, other, ++seq, lane);  // both waves drained
            __atomic_signal_fence(__ATOMIC_RELEASE);
            if (l == 0 && lane == 0) atomicAdd(c1, 1);
        }
    } else {
        // ================= TEAM 2 : layer-2, waves 2/3 =================
        const int l = w - 2;   // 0: W2 half (h1 input), 1: U2 half (h2 input)
        short8 bf0[32], bf1[32];
        {
            const unsigned short* base = P2 + (size_t)ug * (2 * 64 * 512);
            const int fb = l * 32;
            #pragma unroll
            for (int i = 0; i < 32; ++i) {
                bf0[i] = *(const short8*)(base + ((size_t)(0 * 64 + fb + i) * 64 + lane) * 8);
                bf1[i] = *(const short8*)(base + ((size_t)(1 * 64 + fb + i) * 64 + lane) * 8);
            }
        }
        __syncthreads();   // one-time

        volatile int* mine  = &ts2[l];
        volatile int* other = &ts2[1 - l];
        int seq = 0;

        for (int k = 1; k <= T_; ++k) {
            const int t2 = k - 1;
            const bool have = (l == 0) || (k >= 2);
            if (l == 0) wait_ge(c1, 32 * k);          // h1[k-1] ready
            else if (k >= 2) wait_ge(c2, 32 * (k - 1)); // h2[k-2] ready
            __atomic_signal_fence(__ATOMIC_ACQUIRE);

            short8 fB[32];
            if (have) {
                const unsigned short* hb = (l == 0)
                    ? h1r + (size_t)((k - 1) & 3) * BU_ + (size_t)row * U_
                    : h2r + (size_t)((k - 2) & 3) * BU_ + (size_t)row * U_;
                #pragma unroll
                for (int i = 0; i < 32; ++i) fB[i] = llc_load(hb + i * 16 + koff);
            }

            floatx16 a0, a1;
            #pragma unroll
            for (int i = 0; i < 16; ++i) { a0[i] = 0.f; a1[i] = 0.f; }

            if (have) {
                VMWAIT(0);
                #pragma unroll
                for (int i = 0; i < 32; ++i) {
                    dep8(fB[i]);
                    a0 = MFMA32(fB[i], bf0[i], a0);
                    a1 = MFMA32(fB[i], bf1[i], a1);
                }
            }

            #pragma unroll
            for (int r = 0; r < 16; ++r) {
                int rr = (r & 3) + 8 * (r >> 2) + 4 * (lane >> 5);
                redB[l][0][rr][arow] = a0[r];
                redB[l][1][rr][arow] = a1[r];
            }
            tbar(mine, other, ++seq, lane);

            {   // epilogue
                int tt = l * 64 + lane;
                int r  = tt >> 2;
                int q  = tt & 3;
                unsigned int pk0 = 0, pk1 = 0;
                #pragma unroll
                for (int j = 0; j < 4; ++j) {
                    int u = q * 4 + j;
                    float zi = redB[0][0][r][u]      + redB[1][0][r][u];
                    float zf = redB[0][0][r][16 + u] + redB[1][0][r][16 + u];
                    float zg = redB[0][1][r][u]      + redB[1][1][r][u];
                    float zo = redB[0][1][r][16 + u] + redB[1][1][r][16 + u];
                    zi += bias2_s[u];      zf += bias2_s[16 + u];
                    zg += bias2_s[32 + u]; zo += bias2_s[48 + u];
                    float si = 1.f / (1.f + __expf(-zi));
                    float sf = 1.f / (1.f + __expf(-zf));
                    float so = 1.f / (1.f + __expf(-zo));
                    float gg = zg > 0.f ? zg : 0.f;
                    float cn = sf * cst2[r][u] + si * gg;
                    cst2[r][u] = cn;
                    float hn = so * (cn > 0.f ? cn : 0.f);
                    if (j < 2) pk0 |= ((unsigned int)f2bf(hn)) << (16 * j);
                    else       pk1 |= ((unsigned int)f2bf(hn)) << (16 * (j - 2));
                }
                unsigned long long pk = ((unsigned long long)pk1 << 32) | pk0;
                unsigned short* hp = h2r + (size_t)(t2 & 3) * BU_
                                     + (size_t)(mo * 32 + r) * U_ + ug * 16 + q * 4;
                llc_store8(hp, pk);
            }
            VMWAIT(0);
            tbar(mine, other, ++seq, lane);
            __atomic_signal_fence(__ATOMIC_RELEASE);
            if (l == 0 && lane == 0) atomicAdd(c2, 1);
        }
    }
}

__global__ void dense_kernel(const unsigned short* __restrict__ h2,
                             const float* __restrict__ Wd,
                             const float* __restrict__ bd,
                             float* __restrict__ out) {
    int b = blockIdx.x;
    int lane = threadIdx.x;                  // 64 lanes
    const unsigned short* hp = h2 + (long)b * U_ + lane * 8;
    float sum = 0.f;
    #pragma unroll
    for (int j = 0; j < 8; ++j) sum += bf2f(hp[j]) * Wd[lane * 8 + j];
    #pragma unroll
    for (int off = 32; off; off >>= 1) sum += __shfl_down(sum, off);
    if (lane == 0) out[b] = 1.f / (1.f + __expf(-(sum + bd[0])));
}

extern "C" void kernel_launch(void* const* d_in, const int* in_sizes, int n_in,
                              void* d_out, int out_size, void* d_ws, size_t ws_size,
                              hipStream_t stream) {
    const float* x  = (const float*)d_in[0];
    const float* W1 = (const float*)d_in[1];
    const float* U1 = (const float*)d_in[2];
    const float* b1 = (const float*)d_in[3];
    const float* W2 = (const float*)d_in[4];
    const float* U2 = (const float*)d_in[5];
    const float* b2 = (const float*)d_in[6];
    const float* Wd = (const float*)d_in[7];
    const float* bd = (const float*)d_in[8];
    float* out = (float*)d_out;

    char* ws = (char*)d_ws;
    size_t off = 0;
    unsigned short* xb  = (unsigned short*)(ws + off); off += (size_t)B_ * T_ * F_ * 2;      // 8.39 MB
    unsigned short* P1  = (unsigned short*)(ws + off); off += (size_t)32 * 2 * 36 * 512 * 2; // 2.36 MB
    unsigned short* P2  = (unsigned short*)(ws + off); off += (size_t)32 * 2 * 64 * 512 * 2; // 4.19 MB
    unsigned short* h1r = (unsigned short*)(ws + off); off += (size_t)4 * BU_ * 2;           // 1 MB
    unsigned short* h2r = (unsigned short*)(ws + off); off += (size_t)4 * BU_ * 2;           // 1 MB
    int* flags1 = (int*)(ws + off); off += (size_t)8 * 32 * 32 * 4;   // 32 KB (1 line/mo used)
    int* flags2 = (int*)(ws + off); off += (size_t)8 * 32 * 32 * 4;   // 32 KB

    hipMemsetAsync(flags1, 0, (size_t)8 * 32 * 32 * 4 * 2, stream);

    int n = B_ * T_ * F_;
    cast_x_kernel<<<(n + 255) / 256, 256, 0, stream>>>(x, xb, n);
    {
        long tot1 = 32L * 2 * 36 * 512;
        pack32_kernel<<<(int)((tot1 + 255) / 256), 256, 0, stream>>>(W1, U1, P1, 36, 64);
        long tot2 = 32L * 2 * 64 * 512;
        pack32_kernel<<<(int)((tot2 + 255) / 256), 256, 0, stream>>>(W2, U2, P2, 64, 512);
    }

    // 256 blocks = 1 block/CU: co-residency guaranteed, plain launch.
    lstm_persist<<<256, 256, 0, stream>>>(xb, P1, P2, b1, b2, h1r, h2r, flags1, flags2);

    dense_kernel<<<B_, 64, 0, stream>>>(h2r + (size_t)((T_ - 1) & 3) * BU_,
                                        Wd, bd, out);
}